// Round 6
// baseline (11802.805 us; speedup 1.0000x reference)
//
#include <hip/hip_runtime.h>
#include <hip/hip_bf16.h>
#include <math.h>

namespace {

constexpr int B  = 8;
constexpr int N  = 2048;     // power of two: n = p & 2047, b = p >> 11
constexpr int K  = 20;
constexpr int C1 = 64, C2 = 128, C3 = 256;
constexpr int NSLICE = 64;
constexpr double COUNT = 327680.0;   // B*N*K
constexpr double BNEPS = 1e-5;

// ---- workspace layout (bytes) ----
constexpr size_t OFF_IDX1  = 0;                                  // B*N*K int
constexpr size_t OFF_IDX2  = OFF_IDX1 + (size_t)B*N*K*4;         // B*N*K int
constexpr size_t OFF_X1D   = OFF_IDX2 + (size_t)B*N*K*4;         // B*N*C1 f64
constexpr size_t OFF_X2D   = OFF_X1D  + (size_t)B*N*C1*8;        // B*N*C2 f64
constexpr size_t OFF_STATS = OFF_X2D  + (size_t)B*N*C2*8;        // 2*NSLICE*C3 f64
constexpr size_t OFF_MI    = OFF_STATS+ (size_t)2*NSLICE*C3*8;   // 2*C3 f64
constexpr size_t OFF_X2F   = OFF_MI   + 4096;                    // B*N*C2 f32
constexpr size_t OFF_XX2F  = OFF_X2F  + (size_t)B*N*C2*4;        // B*N f32
constexpr size_t OFF_DIST  = OFF_XX2F + (size_t)B*N*4 + 256;     // N*N f32 (per batch)
// total ~70 MB

// ---- strict-rounding f32 helpers (block FMA contraction / reassociation) ----
__device__ __forceinline__ float fmul32(float a, float b){ return __fmul_rn(a,b); }
__device__ __forceinline__ float fadd32(float a, float b){ return __fadd_rn(a,b); }
__device__ __forceinline__ float fsub32(float a, float b){ return __fsub_rn(a,b); }

// ---- per-thread insertion top-20 on f32 (largest, ties keep lowest index) ----
__device__ __forceinline__ void insert_candidatef(float v, int j,
                                                  float (&best)[K], int (&bidx)[K]) {
  if (v > best[K-1]) {
    best[K-1] = v; bidx[K-1] = j;
    #pragma unroll
    for (int i = K-1; i >= 1; --i) {
      if (best[i] > best[i-1]) {
        float tv = best[i]; best[i] = best[i-1]; best[i-1] = tv;
        int   ti = bidx[i]; bidx[i] = bidx[i-1]; bidx[i-1] = ti;
      }
    }
  }
}

// ---- kNN on 3-D coords, numpy-f32-faithful:
// xx = (x0*x0 + x1*x1) + x2*x2 (sequential), inner sequential, no FMA,
// neg_d = (2*inner - xx_i) - xx_j, all f32-rounded per op ----
__global__ __launch_bounds__(64) void knn_xyz_f32(const float* __restrict__ x,
                                                  int* __restrict__ idxo) {
  int row = blockIdx.x * 64 + threadIdx.x;   // grid = B*N/64
  int b = row >> 11, n = row & (N - 1);
  const float* xb = x + (size_t)b * N * 3;
  float xi0 = xb[(size_t)n*3], xi1 = xb[(size_t)n*3+1], xi2 = xb[(size_t)n*3+2];
  float xxi = fadd32(fadd32(fmul32(xi0,xi0), fmul32(xi1,xi1)), fmul32(xi2,xi2));
  float best[K]; int bidx[K];
  #pragma unroll
  for (int i = 0; i < K; ++i) { best[i] = -INFINITY; bidx[i] = 0; }
  for (int j = 0; j < N; ++j) {
    float a = xb[(size_t)j*3], c = xb[(size_t)j*3+1], d = xb[(size_t)j*3+2];
    float xxj   = fadd32(fadd32(fmul32(a,a), fmul32(c,c)), fmul32(d,d));
    float inner = fadd32(fadd32(fmul32(xi0,a), fmul32(xi1,c)), fmul32(xi2,d));
    float v = fsub32(fsub32(fmul32(2.f, inner), xxi), xxj);
    insert_candidatef(v, j, best, bidx);
  }
  int* o = idxo + (size_t)row * K;
  #pragma unroll
  for (int i = 0; i < K; ++i) o[i] = bidx[i];
}

// ---- x2 -> f32 copy + numpy pairwise(n=128) sum of squares:
// r[t]=a[t], t<8; 15 iters of r[t]+=a[i+t]; res=((r0+r1)+(r2+r3))+((r4+r5)+(r6+r7)) ----
__global__ __launch_bounds__(64) void xx2f_kernel(const double* __restrict__ x2d,
                                                  float* __restrict__ x2f,
                                                  float* __restrict__ xx2f) {
  int row = blockIdx.x * 64 + threadIdx.x;   // grid = B*N/64
  const double* src = x2d + (size_t)row * C2;
  float* dst = x2f + (size_t)row * C2;
  float sq[C2];
  #pragma unroll 8
  for (int c = 0; c < C2; ++c) {
    float v = (float)src[c];
    dst[c] = v;
    sq[c] = fmul32(v, v);
  }
  float r0=sq[0], r1=sq[1], r2=sq[2], r3=sq[3], r4=sq[4], r5=sq[5], r6=sq[6], r7=sq[7];
  #pragma unroll
  for (int i = 8; i < 128; i += 8) {
    r0 = fadd32(r0, sq[i+0]); r1 = fadd32(r1, sq[i+1]);
    r2 = fadd32(r2, sq[i+2]); r3 = fadd32(r3, sq[i+3]);
    r4 = fadd32(r4, sq[i+4]); r5 = fadd32(r5, sq[i+5]);
    r6 = fadd32(r6, sq[i+6]); r7 = fadd32(r7, sq[i+7]);
  }
  xx2f[row] = fadd32(fadd32(fadd32(r0,r1), fadd32(r2,r3)),
                     fadd32(fadd32(r4,r5), fadd32(r6,r7)));
}

// ---- per-batch neg-distance matrix, f32 sequential inner (no FMA) ----
__global__ __launch_bounds__(256) void dist_f32_kernel(const float* __restrict__ x2b,
                                                       const float* __restrict__ xx2b,
                                                       float* __restrict__ dist) {
  int ti = blockIdx.y * 64;
  int tj = blockIdx.x * 64;
  int tid = threadIdx.x;
  int tr = tid >> 4, tc = tid & 15;
  __shared__ float A[64][9], Bm[64][9];
  float acc[4][4];
  #pragma unroll
  for (int u = 0; u < 4; ++u)
    #pragma unroll
    for (int v = 0; v < 4; ++v) acc[u][v] = 0.f;
  for (int c0 = 0; c0 < C2; c0 += 8) {
    for (int i = tid; i < 512; i += 256) {
      int r = i >> 3, c = i & 7;
      A[r][c]  = x2b[(size_t)(ti + r)*C2 + c0 + c];
      Bm[r][c] = x2b[(size_t)(tj + r)*C2 + c0 + c];
    }
    __syncthreads();
    #pragma unroll
    for (int c = 0; c < 8; ++c) {       // ascending c: exact sequential order
      float a[4], bv[4];
      #pragma unroll
      for (int u = 0; u < 4; ++u) a[u] = A[tr*4 + u][c];
      #pragma unroll
      for (int v = 0; v < 4; ++v) bv[v] = Bm[tc*4 + v][c];
      #pragma unroll
      for (int u = 0; u < 4; ++u)
        #pragma unroll
        for (int v = 0; v < 4; ++v)
          acc[u][v] = fadd32(acc[u][v], fmul32(a[u], bv[v]));
    }
    __syncthreads();
  }
  #pragma unroll
  for (int u = 0; u < 4; ++u) {
    int i = ti + tr*4 + u;
    float xxi = xx2b[i];
    #pragma unroll
    for (int v = 0; v < 4; ++v) {
      int j = tj + tc*4 + v;
      dist[(size_t)i*N + j] = fsub32(fsub32(fmul32(2.f, acc[u][v]), xxi), xx2b[j]);
    }
  }
}

// ---- per-batch top-k from f32 distance rows ----
__global__ __launch_bounds__(64) void knn_feat_f32(const float* __restrict__ dist,
                                                   int* __restrict__ idxo) {
  int row = blockIdx.x * 64 + threadIdx.x;   // grid = N/64 (per batch)
  const float* dr = dist + (size_t)row * N;
  float best[K]; int bidx[K];
  #pragma unroll
  for (int i = 0; i < K; ++i) { best[i] = -INFINITY; bidx[i] = 0; }
  for (int j = 0; j < N; ++j) insert_candidatef(dr[j], j, best, bidx);
  int* o = idxo + (size_t)row * K;
  #pragma unroll
  for (int i = 0; i < K; ++i) o[i] = bidx[i];
}

// ---- layer 1 (two-pass, f64): geometry + conv1; PASS0 stats, PASS1 BN+max ----
template<int PASS>
__global__ __launch_bounds__(64) void l1_kernel(
    const float* __restrict__ x, const float* __restrict__ nrm,
    const float* __restrict__ w1, const int* __restrict__ idx1,
    double* __restrict__ sS, double* __restrict__ sQ,
    const double* __restrict__ mid, const float* __restrict__ g1, const float* __restrict__ b1,
    double* __restrict__ x1d, float* __restrict__ out448,
    float* __restrict__ outR1, float* __restrict__ outR2) {
  int p = blockIdx.x;
  int tid = threadIdx.x;
  int b = p >> 11, n = p & (N - 1);
  __shared__ float  wl[C1 * 9];
  __shared__ double rotd[K][3];
  __shared__ double fld[K][9];
  for (int i = tid; i < C1 * 9; i += 64) wl[i] = w1[i];
  const float* xb = x + (size_t)b * N * 3;
  double nx = nrm[(size_t)p*3], ny = nrm[(size_t)p*3+1], nz = nrm[(size_t)p*3+2];
  double vx = ny, vy = -nx;
  double s = 1.0 / fmax(1.0 + nz, 1e-8);
  double vxy = vx * vy;
  double R1v[9];
  R1v[0] = 1.0 - s*(vy*vy); R1v[1] = s*vxy;           R1v[2] = vy;
  R1v[3] = s*vxy;           R1v[4] = 1.0 - s*(vx*vx); R1v[5] = -vx;
  R1v[6] = -vy;             R1v[7] = vx;              R1v[8] = 1.0 - s*(vx*vx + vy*vy);
  double xi0 = xb[(size_t)n*3], xi1 = xb[(size_t)n*3+1], xi2 = xb[(size_t)n*3+2];
  if (tid < K) {
    int j = idx1[(size_t)p*K + tid];
    double d0 = (double)xb[(size_t)j*3]   - xi0;
    double d1 = (double)xb[(size_t)j*3+1] - xi1;
    double d2 = (double)xb[(size_t)j*3+2] - xi2;
    rotd[tid][0] = R1v[0]*d0 + R1v[1]*d1 + R1v[2]*d2;
    rotd[tid][1] = R1v[3]*d0 + R1v[4]*d1 + R1v[5]*d2;
    rotd[tid][2] = R1v[6]*d0 + R1v[7]*d1 + R1v[8]*d2;
  }
  __syncthreads();
  double mx = 0.0, my = 0.0;
  #pragma unroll
  for (int k = 0; k < K; ++k) { mx += rotd[k][0]; my += rotd[k][1]; }
  mx /= 20.0; my /= 20.0;
  double r = sqrt(mx*mx + my*my);
  double ct = 1.0, st = 0.0;
  if (r > 0.0) { ct = mx / r; st = my / r; }   // cos/sin of atan2(my,mx)
  if (tid < K) {
    double r0 = rotd[tid][0], r1 = rotd[tid][1], r2 = rotd[tid][2];
    double a0 = ct*r0 + st*r1;
    double a1 = ct*r1 - st*r0;
    fld[tid][0] = a0;  fld[tid][1] = a1;   fld[tid][2] = r2;
    fld[tid][3] = a0;  fld[tid][4] = -a1;  fld[tid][5] = r2;   // xz-mirror
    fld[tid][6] = xi0; fld[tid][7] = xi1;  fld[tid][8] = xi2;  // x_rep
  }
  if (PASS == 0 && tid == 0) {
    float* o1 = outR1 + (size_t)p * 9;
    #pragma unroll
    for (int i = 0; i < 9; ++i) o1[i] = (float)R1v[i];
    float* o2 = outR2 + (size_t)p * 9;
    o2[0] = (float)ct;  o2[1] = (float)st; o2[2] = 0.f;
    o2[3] = (float)-st; o2[4] = (float)ct; o2[5] = 0.f;
    o2[6] = 0.f;        o2[7] = 0.f;       o2[8] = 1.f;
  }
  __syncthreads();
  int o = tid;
  if (PASS == 0) {
    double sum = 0., sq = 0.;
    #pragma unroll
    for (int k = 0; k < K; ++k) {
      double h = 0.;
      #pragma unroll
      for (int c = 0; c < 9; ++c) h = fma((double)wl[o*9 + c], fld[k][c], h);
      sum += h; sq += h*h;
    }
    int slice = p & (NSLICE - 1);
    atomicAdd(&sS[slice*C3 + o], sum);
    atomicAdd(&sQ[slice*C3 + o], sq);
  } else {
    double m = mid[o], is = mid[C3 + o];
    double g = g1[o], bb = b1[o];
    double mxv = -INFINITY;
    #pragma unroll
    for (int k = 0; k < K; ++k) {
      double h = 0.;
      #pragma unroll
      for (int c = 0; c < 9; ++c) h = fma((double)wl[o*9 + c], fld[k][c], h);
      double y = ((h - m) * is) * g + bb;
      y = y > 0.0 ? y : 0.2 * y;
      mxv = fmax(mxv, y);
    }
    x1d[(size_t)p*C1 + o] = mxv;
    out448[(size_t)p*448 + o] = (float)mxv;
  }
}

// ---- layers 2/3 (two-pass, f64), unfolded f = [xj-xi | xi] ----
template<int CIN, int COUT, int PASS>
__global__ __launch_bounds__(COUT) void conv_kernel(
    const double* __restrict__ xind, const int* __restrict__ idx,
    const float* __restrict__ w,
    double* __restrict__ sS, double* __restrict__ sQ,
    const double* __restrict__ mid, const float* __restrict__ gam, const float* __restrict__ bet,
    double* __restrict__ xoutd, float* __restrict__ out448, int outoff) {
  int p = blockIdx.x;
  int tid = threadIdx.x;
  int b = p >> 11;
  __shared__ double xi[CIN];
  __shared__ double fsh[K][2*CIN];
  __shared__ int jidx[K];
  if (tid < K) jidx[tid] = idx[(size_t)p*K + tid];
  if (tid < CIN) xi[tid] = xind[(size_t)p*CIN + tid];
  __syncthreads();
  for (int i = tid; i < K*CIN; i += COUT) {
    int k = i / CIN, c = i % CIN;
    double xj = xind[((size_t)b*N + jidx[k])*CIN + c];
    fsh[k][c]       = xj - xi[c];
    fsh[k][CIN + c] = xi[c];
  }
  __syncthreads();
  const float* wrow = w + (size_t)tid * (2*CIN);
  double acc[K];
  #pragma unroll
  for (int k = 0; k < K; ++k) acc[k] = 0.0;
  #pragma unroll 2
  for (int c = 0; c < 2*CIN; ++c) {
    double wd = (double)wrow[c];
    #pragma unroll
    for (int k = 0; k < K; ++k) acc[k] = fma(wd, fsh[k][c], acc[k]);
  }
  if (PASS == 0) {
    double sum = 0., sq = 0.;
    #pragma unroll
    for (int k = 0; k < K; ++k) { sum += acc[k]; sq += acc[k]*acc[k]; }
    int slice = p & (NSLICE - 1);
    atomicAdd(&sS[slice*C3 + tid], sum);
    atomicAdd(&sQ[slice*C3 + tid], sq);
  } else {
    double m = mid[tid], is = mid[C3 + tid];
    double g = gam[tid], bb = bet[tid];
    double mxv = -INFINITY;
    #pragma unroll
    for (int k = 0; k < K; ++k) {
      double y = ((acc[k] - m) * is) * g + bb;
      y = y > 0.0 ? y : 0.2 * y;
      mxv = fmax(mxv, y);
    }
    if (xoutd) xoutd[(size_t)p*COUT + tid] = mxv;
    out448[(size_t)p*448 + outoff + tid] = (float)mxv;
  }
}

// ---- finalize BN stats (f64) ----
__global__ void finalize_stats(const double* __restrict__ sS, const double* __restrict__ sQ,
                               double* __restrict__ mid, int C) {
  int o = threadIdx.x;
  if (o >= C) return;
  double s = 0., q = 0.;
  for (int i = 0; i < NSLICE; ++i) { s += sS[i*C3 + o]; q += sQ[i*C3 + o]; }
  double m = s / COUNT;
  double v = q / COUNT - m*m;
  mid[o] = m;
  mid[C3 + o] = 1.0 / sqrt(v + BNEPS);
}

} // namespace

extern "C" void kernel_launch(void* const* d_in, const int* in_sizes, int n_in,
                              void* d_out, int out_size, void* d_ws, size_t ws_size,
                              hipStream_t stream) {
  (void)in_sizes; (void)n_in; (void)out_size; (void)ws_size;
  const float* x   = (const float*)d_in[0];
  const float* nrm = (const float*)d_in[1];
  const float* w1  = (const float*)d_in[2];
  const float* g1  = (const float*)d_in[3];
  const float* b1  = (const float*)d_in[4];
  const float* w2  = (const float*)d_in[5];
  const float* g2  = (const float*)d_in[6];
  const float* b2  = (const float*)d_in[7];
  const float* w3  = (const float*)d_in[8];
  const float* g3  = (const float*)d_in[9];
  const float* b3  = (const float*)d_in[10];
  float* out = (float*)d_out;
  char*  ws  = (char*)d_ws;

  int*    idx1 = (int*)(ws + OFF_IDX1);
  int*    idx2 = (int*)(ws + OFF_IDX2);
  double* x1d  = (double*)(ws + OFF_X1D);
  double* x2d  = (double*)(ws + OFF_X2D);
  double* sS   = (double*)(ws + OFF_STATS);
  double* sQ   = sS + (size_t)NSLICE * C3;
  double* mid  = (double*)(ws + OFF_MI);
  float*  x2f  = (float*)(ws + OFF_X2F);
  float*  xx2f = (float*)(ws + OFF_XX2F);
  float*  dist = (float*)(ws + OFF_DIST);   // per-batch

  float* outR1 = out + (size_t)B * N * 448;
  float* outR2 = outR1 + (size_t)B * N * 9;

  // kNN1 — numpy-f32-faithful formula
  knn_xyz_f32<<<B*N/64, 64, 0, stream>>>(x, idx1);

  // layer 1 (f64 two-pass)
  hipMemsetAsync(sS, 0, (size_t)2*NSLICE*C3*sizeof(double), stream);
  l1_kernel<0><<<B*N, 64, 0, stream>>>(x, nrm, w1, idx1, sS, sQ, nullptr, nullptr, nullptr,
                                       nullptr, nullptr, outR1, outR2);
  finalize_stats<<<1, C3, 0, stream>>>(sS, sQ, mid, C1);
  l1_kernel<1><<<B*N, 64, 0, stream>>>(x, nrm, w1, idx1, nullptr, nullptr, mid, g1, b1,
                                       x1d, out, outR1, outR2);

  // layer 2 (f64 two-pass)
  hipMemsetAsync(sS, 0, (size_t)2*NSLICE*C3*sizeof(double), stream);
  conv_kernel<C1, C2, 0><<<B*N, C2, 0, stream>>>(x1d, idx1, w2, sS, sQ, nullptr, nullptr, nullptr,
                                                 nullptr, nullptr, 0);
  finalize_stats<<<1, C3, 0, stream>>>(sS, sQ, mid, C2);
  conv_kernel<C1, C2, 1><<<B*N, C2, 0, stream>>>(x1d, idx1, w2, nullptr, nullptr, mid, g2, b2,
                                                 x2d, out, C1);

  // kNN2 — numpy-f32-faithful: f32-rounded x2, pairwise-128 xx, sequential inner
  xx2f_kernel<<<B*N/64, 64, 0, stream>>>(x2d, x2f, xx2f);
  for (int b = 0; b < B; ++b) {
    dist_f32_kernel<<<dim3(N/64, N/64), 256, 0, stream>>>(x2f + (size_t)b*N*C2,
                                                          xx2f + (size_t)b*N, dist);
    knn_feat_f32<<<N/64, 64, 0, stream>>>(dist, idx2 + (size_t)b*N*K);
  }

  // layer 3 (f64 two-pass)
  hipMemsetAsync(sS, 0, (size_t)2*NSLICE*C3*sizeof(double), stream);
  conv_kernel<C2, C3, 0><<<B*N, C3, 0, stream>>>(x2d, idx2, w3, sS, sQ, nullptr, nullptr, nullptr,
                                                 nullptr, nullptr, 0);
  finalize_stats<<<1, C3, 0, stream>>>(sS, sQ, mid, C3);
  conv_kernel<C2, C3, 1><<<B*N, C3, 0, stream>>>(x2d, idx2, w3, nullptr, nullptr, mid, g3, b3,
                                                 nullptr, out, C1 + C2);
}

// Round 7
// 4142.344 us; speedup vs baseline: 2.8493x; 2.8493x over previous
//
#include <hip/hip_runtime.h>
#include <hip/hip_bf16.h>
#include <math.h>

namespace {

constexpr int B  = 8;
constexpr int N  = 2048;     // power of two: n = p & 2047, b = p >> 11
constexpr int K  = 20;
constexpr int C1 = 64, C2 = 128, C3 = 256;
constexpr int NSLICE = 64;
constexpr double COUNT = 327680.0;   // B*N*K
constexpr double BNEPS = 1e-5;

// ---- workspace layout (bytes) ----
constexpr size_t OFF_IDX1  = 0;                                  // B*N*K int
constexpr size_t OFF_IDX2  = OFF_IDX1 + (size_t)B*N*K*4;         // B*N*K int
constexpr size_t OFF_X1D   = OFF_IDX2 + (size_t)B*N*K*4;         // B*N*C1 f64
constexpr size_t OFF_X2D   = OFF_X1D  + (size_t)B*N*C1*8;        // B*N*C2 f64
constexpr size_t OFF_STATS = OFF_X2D  + (size_t)B*N*C2*8;        // 2*NSLICE*C3 f64
constexpr size_t OFF_MI    = OFF_STATS+ (size_t)2*NSLICE*C3*8;   // 2*C3 f64
constexpr size_t OFF_X2F   = OFF_MI   + 4096;                    // B*N*C2 f32
constexpr size_t OFF_XX2F  = OFF_X2F  + (size_t)B*N*C2*4;        // B*N f32
constexpr size_t OFF_DIST  = OFF_XX2F + (size_t)B*N*4;           // B*N*N f32 (all batches)
// total = OFF_DIST + 134217728 ≈ 162 MB

// ---- strict-rounding f32 helpers (block FMA contraction / reassociation) ----
__device__ __forceinline__ float fmul32(float a, float b){ return __fmul_rn(a,b); }
__device__ __forceinline__ float fadd32(float a, float b){ return __fadd_rn(a,b); }
__device__ __forceinline__ float fsub32(float a, float b){ return __fsub_rn(a,b); }

// ---- per-thread insertion top-20 on f32 (largest, ties keep lowest index) ----
__device__ __forceinline__ void insert_candidatef(float v, int j,
                                                  float (&best)[K], int (&bidx)[K]) {
  if (v > best[K-1]) {
    best[K-1] = v; bidx[K-1] = j;
    #pragma unroll
    for (int i = K-1; i >= 1; --i) {
      if (best[i] > best[i-1]) {
        float tv = best[i]; best[i] = best[i-1]; best[i-1] = tv;
        int   ti = bidx[i]; bidx[i] = bidx[i-1]; bidx[i-1] = ti;
      }
    }
  }
}

// ---- kNN on 3-D coords, numpy-f32-faithful (BIT-FROZEN) ----
__global__ __launch_bounds__(64) void knn_xyz_f32(const float* __restrict__ x,
                                                  int* __restrict__ idxo) {
  int row = blockIdx.x * 64 + threadIdx.x;   // grid = B*N/64
  int b = row >> 11, n = row & (N - 1);
  const float* xb = x + (size_t)b * N * 3;
  float xi0 = xb[(size_t)n*3], xi1 = xb[(size_t)n*3+1], xi2 = xb[(size_t)n*3+2];
  float xxi = fadd32(fadd32(fmul32(xi0,xi0), fmul32(xi1,xi1)), fmul32(xi2,xi2));
  float best[K]; int bidx[K];
  #pragma unroll
  for (int i = 0; i < K; ++i) { best[i] = -INFINITY; bidx[i] = 0; }
  for (int j = 0; j < N; ++j) {
    float a = xb[(size_t)j*3], c = xb[(size_t)j*3+1], d = xb[(size_t)j*3+2];
    float xxj   = fadd32(fadd32(fmul32(a,a), fmul32(c,c)), fmul32(d,d));
    float inner = fadd32(fadd32(fmul32(xi0,a), fmul32(xi1,c)), fmul32(xi2,d));
    float v = fsub32(fsub32(fmul32(2.f, inner), xxi), xxj);
    insert_candidatef(v, j, best, bidx);
  }
  int* o = idxo + (size_t)row * K;
  #pragma unroll
  for (int i = 0; i < K; ++i) o[i] = bidx[i];
}

// ---- x2 -> f32 copy + numpy pairwise(n=128) sum of squares (BIT-FROZEN) ----
__global__ __launch_bounds__(64) void xx2f_kernel(const double* __restrict__ x2d,
                                                  float* __restrict__ x2f,
                                                  float* __restrict__ xx2f) {
  int row = blockIdx.x * 64 + threadIdx.x;   // grid = B*N/64
  const double* src = x2d + (size_t)row * C2;
  float* dst = x2f + (size_t)row * C2;
  float sq[C2];
  #pragma unroll 8
  for (int c = 0; c < C2; ++c) {
    float v = (float)src[c];
    dst[c] = v;
    sq[c] = fmul32(v, v);
  }
  float r0=sq[0], r1=sq[1], r2=sq[2], r3=sq[3], r4=sq[4], r5=sq[5], r6=sq[6], r7=sq[7];
  #pragma unroll
  for (int i = 8; i < 128; i += 8) {
    r0 = fadd32(r0, sq[i+0]); r1 = fadd32(r1, sq[i+1]);
    r2 = fadd32(r2, sq[i+2]); r3 = fadd32(r3, sq[i+3]);
    r4 = fadd32(r4, sq[i+4]); r5 = fadd32(r5, sq[i+5]);
    r6 = fadd32(r6, sq[i+6]); r7 = fadd32(r7, sq[i+7]);
  }
  xx2f[row] = fadd32(fadd32(fadd32(r0,r1), fadd32(r2,r3)),
                     fadd32(fadd32(r4,r5), fadd32(r6,r7)));
}

// ---- all-batch neg-distance matrix, f32 sequential (BIT-FROZEN inner) ----
__global__ __launch_bounds__(256) void dist_f32_kernel(const float* __restrict__ x2f,
                                                       const float* __restrict__ xx2f,
                                                       float* __restrict__ dist) {
  int bz = blockIdx.z;
  const float* x2b  = x2f  + (size_t)bz * N * C2;
  const float* xx2b = xx2f + (size_t)bz * N;
  float* db = dist + (size_t)bz * N * N;
  int ti = blockIdx.y * 64;
  int tj = blockIdx.x * 64;
  int tid = threadIdx.x;
  int tr = tid >> 4, tc = tid & 15;
  __shared__ float A[64][9], Bm[64][9];
  float acc[4][4];
  #pragma unroll
  for (int u = 0; u < 4; ++u)
    #pragma unroll
    for (int v = 0; v < 4; ++v) acc[u][v] = 0.f;
  for (int c0 = 0; c0 < C2; c0 += 8) {
    for (int i = tid; i < 512; i += 256) {
      int r = i >> 3, c = i & 7;
      A[r][c]  = x2b[(size_t)(ti + r)*C2 + c0 + c];
      Bm[r][c] = x2b[(size_t)(tj + r)*C2 + c0 + c];
    }
    __syncthreads();
    #pragma unroll
    for (int c = 0; c < 8; ++c) {       // ascending c: exact sequential order
      float a[4], bv[4];
      #pragma unroll
      for (int u = 0; u < 4; ++u) a[u] = A[tr*4 + u][c];
      #pragma unroll
      for (int v = 0; v < 4; ++v) bv[v] = Bm[tc*4 + v][c];
      #pragma unroll
      for (int u = 0; u < 4; ++u)
        #pragma unroll
        for (int v = 0; v < 4; ++v)
          acc[u][v] = fadd32(acc[u][v], fmul32(a[u], bv[v]));
    }
    __syncthreads();
  }
  #pragma unroll
  for (int u = 0; u < 4; ++u) {
    int i = ti + tr*4 + u;
    float xxi = xx2b[i];
    #pragma unroll
    for (int v = 0; v < 4; ++v) {
      int j = tj + tc*4 + v;
      db[(size_t)i*N + j] = fsub32(fsub32(fmul32(2.f, acc[u][v]), xxi), xx2b[j]);
    }
  }
}

// ---- all-batch top-k from f32 distance rows (BIT-FROZEN) ----
__global__ __launch_bounds__(64) void knn_feat_f32(const float* __restrict__ dist,
                                                   int* __restrict__ idxo) {
  int row = blockIdx.x * 64 + threadIdx.x;   // grid = B*N/64
  const float* dr = dist + (size_t)row * N;
  float best[K]; int bidx[K];
  #pragma unroll
  for (int i = 0; i < K; ++i) { best[i] = -INFINITY; bidx[i] = 0; }
  for (int j = 0; j < N; ++j) insert_candidatef(dr[j], j, best, bidx);
  int* o = idxo + (size_t)row * K;
  #pragma unroll
  for (int i = 0; i < K; ++i) o[i] = bidx[i];
}

// ---- layer 1 (two-pass, f64): geometry + conv1 (BIT-FROZEN) ----
template<int PASS>
__global__ __launch_bounds__(64) void l1_kernel(
    const float* __restrict__ x, const float* __restrict__ nrm,
    const float* __restrict__ w1, const int* __restrict__ idx1,
    double* __restrict__ sS, double* __restrict__ sQ,
    const double* __restrict__ mid, const float* __restrict__ g1, const float* __restrict__ b1,
    double* __restrict__ x1d, float* __restrict__ out448,
    float* __restrict__ outR1, float* __restrict__ outR2) {
  int p = blockIdx.x;
  int tid = threadIdx.x;
  int b = p >> 11, n = p & (N - 1);
  __shared__ float  wl[C1 * 9];
  __shared__ double rotd[K][3];
  __shared__ double fld[K][9];
  for (int i = tid; i < C1 * 9; i += 64) wl[i] = w1[i];
  const float* xb = x + (size_t)b * N * 3;
  double nx = nrm[(size_t)p*3], ny = nrm[(size_t)p*3+1], nz = nrm[(size_t)p*3+2];
  double vx = ny, vy = -nx;
  double s = 1.0 / fmax(1.0 + nz, 1e-8);
  double vxy = vx * vy;
  double R1v[9];
  R1v[0] = 1.0 - s*(vy*vy); R1v[1] = s*vxy;           R1v[2] = vy;
  R1v[3] = s*vxy;           R1v[4] = 1.0 - s*(vx*vx); R1v[5] = -vx;
  R1v[6] = -vy;             R1v[7] = vx;              R1v[8] = 1.0 - s*(vx*vx + vy*vy);
  double xi0 = xb[(size_t)n*3], xi1 = xb[(size_t)n*3+1], xi2 = xb[(size_t)n*3+2];
  if (tid < K) {
    int j = idx1[(size_t)p*K + tid];
    double d0 = (double)xb[(size_t)j*3]   - xi0;
    double d1 = (double)xb[(size_t)j*3+1] - xi1;
    double d2 = (double)xb[(size_t)j*3+2] - xi2;
    rotd[tid][0] = R1v[0]*d0 + R1v[1]*d1 + R1v[2]*d2;
    rotd[tid][1] = R1v[3]*d0 + R1v[4]*d1 + R1v[5]*d2;
    rotd[tid][2] = R1v[6]*d0 + R1v[7]*d1 + R1v[8]*d2;
  }
  __syncthreads();
  double mx = 0.0, my = 0.0;
  #pragma unroll
  for (int k = 0; k < K; ++k) { mx += rotd[k][0]; my += rotd[k][1]; }
  mx /= 20.0; my /= 20.0;
  double r = sqrt(mx*mx + my*my);
  double ct = 1.0, st = 0.0;
  if (r > 0.0) { ct = mx / r; st = my / r; }   // cos/sin of atan2(my,mx)
  if (tid < K) {
    double r0 = rotd[tid][0], r1 = rotd[tid][1], r2 = rotd[tid][2];
    double a0 = ct*r0 + st*r1;
    double a1 = ct*r1 - st*r0;
    fld[tid][0] = a0;  fld[tid][1] = a1;   fld[tid][2] = r2;
    fld[tid][3] = a0;  fld[tid][4] = -a1;  fld[tid][5] = r2;   // xz-mirror
    fld[tid][6] = xi0; fld[tid][7] = xi1;  fld[tid][8] = xi2;  // x_rep
  }
  if (PASS == 0 && tid == 0) {
    float* o1 = outR1 + (size_t)p * 9;
    #pragma unroll
    for (int i = 0; i < 9; ++i) o1[i] = (float)R1v[i];
    float* o2 = outR2 + (size_t)p * 9;
    o2[0] = (float)ct;  o2[1] = (float)st; o2[2] = 0.f;
    o2[3] = (float)-st; o2[4] = (float)ct; o2[5] = 0.f;
    o2[6] = 0.f;        o2[7] = 0.f;       o2[8] = 1.f;
  }
  __syncthreads();
  int o = tid;
  if (PASS == 0) {
    double sum = 0., sq = 0.;
    #pragma unroll
    for (int k = 0; k < K; ++k) {
      double h = 0.;
      #pragma unroll
      for (int c = 0; c < 9; ++c) h = fma((double)wl[o*9 + c], fld[k][c], h);
      sum += h; sq += h*h;
    }
    int slice = p & (NSLICE - 1);
    atomicAdd(&sS[slice*C3 + o], sum);
    atomicAdd(&sQ[slice*C3 + o], sq);
  } else {
    double m = mid[o], is = mid[C3 + o];
    double g = g1[o], bb = b1[o];
    double mxv = -INFINITY;
    #pragma unroll
    for (int k = 0; k < K; ++k) {
      double h = 0.;
      #pragma unroll
      for (int c = 0; c < 9; ++c) h = fma((double)wl[o*9 + c], fld[k][c], h);
      double y = ((h - m) * is) * g + bb;
      y = y > 0.0 ? y : 0.2 * y;
      mxv = fmax(mxv, y);
    }
    x1d[(size_t)p*C1 + o] = mxv;
    out448[(size_t)p*448 + o] = (float)mxv;
  }
}

// ---- conv2 (two-pass, f64): scalar-uniform operands, BIT-EXACT same op
// sequence as the LDS version: per acc[k], phase1 c=0..63 fma(w[c], xj-xi),
// then phase2 c=0..63 fma(w[64+c], xi). ----
template<int PASS>
__global__ __launch_bounds__(128) void conv2_kernel(
    const double* __restrict__ x1d, const int* __restrict__ idx,
    const float* __restrict__ w,
    double* __restrict__ sS, double* __restrict__ sQ,
    const double* __restrict__ mid, const float* __restrict__ gam, const float* __restrict__ bet,
    double* __restrict__ x2d, float* __restrict__ out448) {
  int p = blockIdx.x;
  int tid = threadIdx.x;
  int b = p >> 11;
  int jr[K];
  #pragma unroll
  for (int k = 0; k < K; ++k)
    jr[k] = __builtin_amdgcn_readfirstlane(idx[(size_t)p*K + k]);
  const double* xiR = x1d + (size_t)p * C1;
  const float*  wr  = w + (size_t)tid * (2*C1);
  double acc[K];
  #pragma unroll
  for (int k = 0; k < K; ++k) acc[k] = 0.0;
  // phase 1: diff operand, c ascending
  for (int c0 = 0; c0 < C1; c0 += 16) {
    double wd[16], xiv[16];
    #pragma unroll
    for (int i = 0; i < 16; ++i) { wd[i] = (double)wr[c0+i]; xiv[i] = xiR[c0+i]; }
    #pragma unroll
    for (int k = 0; k < K; ++k) {
      const double* xjR = x1d + ((size_t)b*N + jr[k]) * C1 + c0;
      #pragma unroll
      for (int i = 0; i < 16; ++i) acc[k] = fma(wd[i], xjR[i] - xiv[i], acc[k]);
    }
  }
  // phase 2: x_rep operand, c ascending
  for (int c0 = 0; c0 < C1; c0 += 16) {
    double wd[16], xiv[16];
    #pragma unroll
    for (int i = 0; i < 16; ++i) { wd[i] = (double)wr[C1+c0+i]; xiv[i] = xiR[c0+i]; }
    #pragma unroll
    for (int k = 0; k < K; ++k) {
      #pragma unroll
      for (int i = 0; i < 16; ++i) acc[k] = fma(wd[i], xiv[i], acc[k]);
    }
  }
  if (PASS == 0) {
    double sum = 0., sq = 0.;
    #pragma unroll
    for (int k = 0; k < K; ++k) { sum += acc[k]; sq += acc[k]*acc[k]; }
    int slice = p & (NSLICE - 1);
    atomicAdd(&sS[slice*C3 + tid], sum);
    atomicAdd(&sQ[slice*C3 + tid], sq);
  } else {
    double m = mid[tid], is = mid[C3 + tid];
    double g = gam[tid], bb = bet[tid];
    double mxv = -INFINITY;
    #pragma unroll
    for (int k = 0; k < K; ++k) {
      double y = ((acc[k] - m) * is) * g + bb;
      y = y > 0.0 ? y : 0.2 * y;
      mxv = fmax(mxv, y);
    }
    x2d[(size_t)p*C2 + tid] = mxv;
    out448[(size_t)p*448 + C1 + tid] = (float)mxv;
  }
}

// ---- conv3 (two-pass, f32, value path): folded algebra + scalar-uniform xj ----
template<int PASS>
__global__ __launch_bounds__(256) void conv3_kernel(
    const float* __restrict__ x2f, const int* __restrict__ idx,
    const float* __restrict__ w,
    double* __restrict__ sS, double* __restrict__ sQ,
    const double* __restrict__ mid, const float* __restrict__ gam, const float* __restrict__ bet,
    float* __restrict__ out448) {
  int p = blockIdx.x;
  int tid = threadIdx.x;
  int b = p >> 11;
  int jr[K];
  #pragma unroll
  for (int k = 0; k < K; ++k)
    jr[k] = __builtin_amdgcn_readfirstlane(idx[(size_t)p*K + k]);
  const float* xiR = x2f + (size_t)p * C2;
  const float* wr  = w + (size_t)tid * (2*C2);
  float base = 0.f;
  for (int c0 = 0; c0 < C2; c0 += 32) {
    #pragma unroll
    for (int i = 0; i < 32; ++i)
      base = fmaf(wr[C2+c0+i] - wr[c0+i], xiR[c0+i], base);
  }
  float acc[K];
  #pragma unroll
  for (int k = 0; k < K; ++k) acc[k] = base;
  for (int c0 = 0; c0 < C2; c0 += 32) {
    float wd[32];
    #pragma unroll
    for (int i = 0; i < 32; ++i) wd[i] = wr[c0+i];
    #pragma unroll
    for (int k = 0; k < K; ++k) {
      const float* xjR = x2f + ((size_t)b*N + jr[k]) * C2 + c0;
      #pragma unroll
      for (int i = 0; i < 32; ++i) acc[k] = fmaf(wd[i], xjR[i], acc[k]);
    }
  }
  if (PASS == 0) {
    double sum = 0., sq = 0.;
    #pragma unroll
    for (int k = 0; k < K; ++k) {
      double h = (double)acc[k];
      sum += h; sq += h*h;
    }
    int slice = p & (NSLICE - 1);
    atomicAdd(&sS[slice*C3 + tid], sum);
    atomicAdd(&sQ[slice*C3 + tid], sq);
  } else {
    float m = (float)mid[tid], is = (float)mid[C3 + tid];
    float g = gam[tid], bb = bet[tid];
    float mxv = -INFINITY;
    #pragma unroll
    for (int k = 0; k < K; ++k) {
      float y = (acc[k] - m) * is * g + bb;
      y = y > 0.f ? y : 0.2f * y;
      mxv = fmaxf(mxv, y);
    }
    out448[(size_t)p*448 + C1 + C2 + tid] = mxv;
  }
}

// ---- finalize BN stats (f64) ----
__global__ void finalize_stats(const double* __restrict__ sS, const double* __restrict__ sQ,
                               double* __restrict__ mid, int C) {
  int o = threadIdx.x;
  if (o >= C) return;
  double s = 0., q = 0.;
  for (int i = 0; i < NSLICE; ++i) { s += sS[i*C3 + o]; q += sQ[i*C3 + o]; }
  double m = s / COUNT;
  double v = q / COUNT - m*m;
  mid[o] = m;
  mid[C3 + o] = 1.0 / sqrt(v + BNEPS);
}

} // namespace

extern "C" void kernel_launch(void* const* d_in, const int* in_sizes, int n_in,
                              void* d_out, int out_size, void* d_ws, size_t ws_size,
                              hipStream_t stream) {
  (void)in_sizes; (void)n_in; (void)out_size; (void)ws_size;
  const float* x   = (const float*)d_in[0];
  const float* nrm = (const float*)d_in[1];
  const float* w1  = (const float*)d_in[2];
  const float* g1  = (const float*)d_in[3];
  const float* b1  = (const float*)d_in[4];
  const float* w2  = (const float*)d_in[5];
  const float* g2  = (const float*)d_in[6];
  const float* b2  = (const float*)d_in[7];
  const float* w3  = (const float*)d_in[8];
  const float* g3  = (const float*)d_in[9];
  const float* b3  = (const float*)d_in[10];
  float* out = (float*)d_out;
  char*  ws  = (char*)d_ws;

  int*    idx1 = (int*)(ws + OFF_IDX1);
  int*    idx2 = (int*)(ws + OFF_IDX2);
  double* x1d  = (double*)(ws + OFF_X1D);
  double* x2d  = (double*)(ws + OFF_X2D);
  double* sS   = (double*)(ws + OFF_STATS);
  double* sQ   = sS + (size_t)NSLICE * C3;
  double* mid  = (double*)(ws + OFF_MI);
  float*  x2f  = (float*)(ws + OFF_X2F);
  float*  xx2f = (float*)(ws + OFF_XX2F);
  float*  dist = (float*)(ws + OFF_DIST);   // all batches

  float* outR1 = out + (size_t)B * N * 448;
  float* outR2 = outR1 + (size_t)B * N * 9;

  // kNN1 — numpy-f32-faithful formula
  knn_xyz_f32<<<B*N/64, 64, 0, stream>>>(x, idx1);

  // layer 1 (f64 two-pass)
  hipMemsetAsync(sS, 0, (size_t)2*NSLICE*C3*sizeof(double), stream);
  l1_kernel<0><<<B*N, 64, 0, stream>>>(x, nrm, w1, idx1, sS, sQ, nullptr, nullptr, nullptr,
                                       nullptr, nullptr, outR1, outR2);
  finalize_stats<<<1, C3, 0, stream>>>(sS, sQ, mid, C1);
  l1_kernel<1><<<B*N, 64, 0, stream>>>(x, nrm, w1, idx1, nullptr, nullptr, mid, g1, b1,
                                       x1d, out, outR1, outR2);

  // layer 2 (f64 two-pass, scalar-uniform, bit-exact op order)
  hipMemsetAsync(sS, 0, (size_t)2*NSLICE*C3*sizeof(double), stream);
  conv2_kernel<0><<<B*N, 128, 0, stream>>>(x1d, idx1, w2, sS, sQ, nullptr, nullptr, nullptr,
                                           nullptr, nullptr);
  finalize_stats<<<1, C3, 0, stream>>>(sS, sQ, mid, C2);
  conv2_kernel<1><<<B*N, 128, 0, stream>>>(x1d, idx1, w2, nullptr, nullptr, mid, g2, b2,
                                           x2d, out);

  // kNN2 — numpy-f32-faithful, all batches fused
  xx2f_kernel<<<B*N/64, 64, 0, stream>>>(x2d, x2f, xx2f);
  dist_f32_kernel<<<dim3(N/64, N/64, B), 256, 0, stream>>>(x2f, xx2f, dist);
  knn_feat_f32<<<B*N/64, 64, 0, stream>>>(dist, idx2);

  // layer 3 (f32 two-pass, folded, value path)
  hipMemsetAsync(sS, 0, (size_t)2*NSLICE*C3*sizeof(double), stream);
  conv3_kernel<0><<<B*N, 256, 0, stream>>>(x2f, idx2, w3, sS, sQ, nullptr, nullptr, nullptr,
                                           nullptr);
  finalize_stats<<<1, C3, 0, stream>>>(sS, sQ, mid, C3);
  conv3_kernel<1><<<B*N, 256, 0, stream>>>(x2f, idx2, w3, nullptr, nullptr, mid, g3, b3,
                                           out);
}

// Round 8
// 3437.262 us; speedup vs baseline: 3.4338x; 1.2051x over previous
//
#include <hip/hip_runtime.h>
#include <hip/hip_bf16.h>
#include <math.h>

namespace {

constexpr int B  = 8;
constexpr int N  = 2048;     // power of two: n = p & 2047, b = p >> 11
constexpr int K  = 20;
constexpr int C1 = 64, C2 = 128, C3 = 256;
constexpr int NSLICE = 64;
constexpr double COUNT = 327680.0;   // B*N*K
constexpr double BNEPS = 1e-5;

// ---- workspace layout (bytes) ----
constexpr size_t OFF_IDX1  = 0;                                  // B*N*K int
constexpr size_t OFF_IDX2  = OFF_IDX1 + (size_t)B*N*K*4;         // B*N*K int
constexpr size_t OFF_X1D   = OFF_IDX2 + (size_t)B*N*K*4;         // B*N*C1 f64
constexpr size_t OFF_X2D   = OFF_X1D  + (size_t)B*N*C1*8;        // B*N*C2 f64
constexpr size_t OFF_STATS = OFF_X2D  + (size_t)B*N*C2*8;        // 2*NSLICE*C3 f64
constexpr size_t OFF_MI    = OFF_STATS+ (size_t)2*NSLICE*C3*8;   // 2*C3 f64
constexpr size_t OFF_X2F   = OFF_MI   + 4096;                    // B*N*C2 f32
constexpr size_t OFF_XX2F  = OFF_X2F  + (size_t)B*N*C2*4;        // B*N f32
constexpr size_t OFF_DIST  = OFF_XX2F + (size_t)B*N*4;           // B*N*N f32 (all batches)
// total = OFF_DIST + 134217728 ≈ 162 MB

// ---- strict-rounding f32 helpers (block FMA contraction / reassociation) ----
__device__ __forceinline__ float fmul32(float a, float b){ return __fmul_rn(a,b); }
__device__ __forceinline__ float fadd32(float a, float b){ return __fadd_rn(a,b); }
__device__ __forceinline__ float fsub32(float a, float b){ return __fsub_rn(a,b); }

// ---- per-thread insertion top-20 on f32 (largest, ties keep lowest index) ----
__device__ __forceinline__ void insert_candidatef(float v, int j,
                                                  float (&best)[K], int (&bidx)[K]) {
  if (v > best[K-1]) {
    best[K-1] = v; bidx[K-1] = j;
    #pragma unroll
    for (int i = K-1; i >= 1; --i) {
      if (best[i] > best[i-1]) {
        float tv = best[i]; best[i] = best[i-1]; best[i-1] = tv;
        int   ti = bidx[i]; bidx[i] = bidx[i-1]; bidx[i-1] = ti;
      }
    }
  }
}

// ---- kNN on 3-D coords, numpy-f32-faithful (BIT-FROZEN) ----
__global__ __launch_bounds__(64) void knn_xyz_f32(const float* __restrict__ x,
                                                  int* __restrict__ idxo) {
  int row = blockIdx.x * 64 + threadIdx.x;   // grid = B*N/64
  int b = row >> 11, n = row & (N - 1);
  const float* xb = x + (size_t)b * N * 3;
  float xi0 = xb[(size_t)n*3], xi1 = xb[(size_t)n*3+1], xi2 = xb[(size_t)n*3+2];
  float xxi = fadd32(fadd32(fmul32(xi0,xi0), fmul32(xi1,xi1)), fmul32(xi2,xi2));
  float best[K]; int bidx[K];
  #pragma unroll
  for (int i = 0; i < K; ++i) { best[i] = -INFINITY; bidx[i] = 0; }
  for (int j = 0; j < N; ++j) {
    float a = xb[(size_t)j*3], c = xb[(size_t)j*3+1], d = xb[(size_t)j*3+2];
    float xxj   = fadd32(fadd32(fmul32(a,a), fmul32(c,c)), fmul32(d,d));
    float inner = fadd32(fadd32(fmul32(xi0,a), fmul32(xi1,c)), fmul32(xi2,d));
    float v = fsub32(fsub32(fmul32(2.f, inner), xxi), xxj);
    insert_candidatef(v, j, best, bidx);
  }
  int* o = idxo + (size_t)row * K;
  #pragma unroll
  for (int i = 0; i < K; ++i) o[i] = bidx[i];
}

// ---- x2 -> f32 copy + numpy pairwise(n=128) sum of squares (BIT-FROZEN) ----
__global__ __launch_bounds__(64) void xx2f_kernel(const double* __restrict__ x2d,
                                                  float* __restrict__ x2f,
                                                  float* __restrict__ xx2f) {
  int row = blockIdx.x * 64 + threadIdx.x;   // grid = B*N/64
  const double* src = x2d + (size_t)row * C2;
  float* dst = x2f + (size_t)row * C2;
  float sq[C2];
  #pragma unroll 8
  for (int c = 0; c < C2; ++c) {
    float v = (float)src[c];
    dst[c] = v;
    sq[c] = fmul32(v, v);
  }
  float r0=sq[0], r1=sq[1], r2=sq[2], r3=sq[3], r4=sq[4], r5=sq[5], r6=sq[6], r7=sq[7];
  #pragma unroll
  for (int i = 8; i < 128; i += 8) {
    r0 = fadd32(r0, sq[i+0]); r1 = fadd32(r1, sq[i+1]);
    r2 = fadd32(r2, sq[i+2]); r3 = fadd32(r3, sq[i+3]);
    r4 = fadd32(r4, sq[i+4]); r5 = fadd32(r5, sq[i+5]);
    r6 = fadd32(r6, sq[i+6]); r7 = fadd32(r7, sq[i+7]);
  }
  xx2f[row] = fadd32(fadd32(fadd32(r0,r1), fadd32(r2,r3)),
                     fadd32(fadd32(r4,r5), fadd32(r6,r7)));
}

// ---- all-batch neg-distance matrix, f32 sequential (BIT-FROZEN inner) ----
__global__ __launch_bounds__(256) void dist_f32_kernel(const float* __restrict__ x2f,
                                                       const float* __restrict__ xx2f,
                                                       float* __restrict__ dist) {
  int bz = blockIdx.z;
  const float* x2b  = x2f  + (size_t)bz * N * C2;
  const float* xx2b = xx2f + (size_t)bz * N;
  float* db = dist + (size_t)bz * N * N;
  int ti = blockIdx.y * 64;
  int tj = blockIdx.x * 64;
  int tid = threadIdx.x;
  int tr = tid >> 4, tc = tid & 15;
  __shared__ float A[64][9], Bm[64][9];
  float acc[4][4];
  #pragma unroll
  for (int u = 0; u < 4; ++u)
    #pragma unroll
    for (int v = 0; v < 4; ++v) acc[u][v] = 0.f;
  for (int c0 = 0; c0 < C2; c0 += 8) {
    for (int i = tid; i < 512; i += 256) {
      int r = i >> 3, c = i & 7;
      A[r][c]  = x2b[(size_t)(ti + r)*C2 + c0 + c];
      Bm[r][c] = x2b[(size_t)(tj + r)*C2 + c0 + c];
    }
    __syncthreads();
    #pragma unroll
    for (int c = 0; c < 8; ++c) {       // ascending c: exact sequential order
      float a[4], bv[4];
      #pragma unroll
      for (int u = 0; u < 4; ++u) a[u] = A[tr*4 + u][c];
      #pragma unroll
      for (int v = 0; v < 4; ++v) bv[v] = Bm[tc*4 + v][c];
      #pragma unroll
      for (int u = 0; u < 4; ++u)
        #pragma unroll
        for (int v = 0; v < 4; ++v)
          acc[u][v] = fadd32(acc[u][v], fmul32(a[u], bv[v]));
    }
    __syncthreads();
  }
  #pragma unroll
  for (int u = 0; u < 4; ++u) {
    int i = ti + tr*4 + u;
    float xxi = xx2b[i];
    #pragma unroll
    for (int v = 0; v < 4; ++v) {
      int j = tj + tc*4 + v;
      db[(size_t)i*N + j] = fsub32(fsub32(fmul32(2.f, acc[u][v]), xxi), xx2b[j]);
    }
  }
}

// ---- all-batch top-k from f32 distance rows (BIT-FROZEN) ----
__global__ __launch_bounds__(64) void knn_feat_f32(const float* __restrict__ dist,
                                                   int* __restrict__ idxo) {
  int row = blockIdx.x * 64 + threadIdx.x;   // grid = B*N/64
  const float* dr = dist + (size_t)row * N;
  float best[K]; int bidx[K];
  #pragma unroll
  for (int i = 0; i < K; ++i) { best[i] = -INFINITY; bidx[i] = 0; }
  for (int j = 0; j < N; ++j) insert_candidatef(dr[j], j, best, bidx);
  int* o = idxo + (size_t)row * K;
  #pragma unroll
  for (int i = 0; i < K; ++i) o[i] = bidx[i];
}

// ---- layer 1 (two-pass, f64): geometry + conv1 (BIT-FROZEN) ----
template<int PASS>
__global__ __launch_bounds__(64) void l1_kernel(
    const float* __restrict__ x, const float* __restrict__ nrm,
    const float* __restrict__ w1, const int* __restrict__ idx1,
    double* __restrict__ sS, double* __restrict__ sQ,
    const double* __restrict__ mid, const float* __restrict__ g1, const float* __restrict__ b1,
    double* __restrict__ x1d, float* __restrict__ out448,
    float* __restrict__ outR1, float* __restrict__ outR2) {
  int p = blockIdx.x;
  int tid = threadIdx.x;
  int b = p >> 11, n = p & (N - 1);
  __shared__ float  wl[C1 * 9];
  __shared__ double rotd[K][3];
  __shared__ double fld[K][9];
  for (int i = tid; i < C1 * 9; i += 64) wl[i] = w1[i];
  const float* xb = x + (size_t)b * N * 3;
  double nx = nrm[(size_t)p*3], ny = nrm[(size_t)p*3+1], nz = nrm[(size_t)p*3+2];
  double vx = ny, vy = -nx;
  double s = 1.0 / fmax(1.0 + nz, 1e-8);
  double vxy = vx * vy;
  double R1v[9];
  R1v[0] = 1.0 - s*(vy*vy); R1v[1] = s*vxy;           R1v[2] = vy;
  R1v[3] = s*vxy;           R1v[4] = 1.0 - s*(vx*vx); R1v[5] = -vx;
  R1v[6] = -vy;             R1v[7] = vx;              R1v[8] = 1.0 - s*(vx*vx + vy*vy);
  double xi0 = xb[(size_t)n*3], xi1 = xb[(size_t)n*3+1], xi2 = xb[(size_t)n*3+2];
  if (tid < K) {
    int j = idx1[(size_t)p*K + tid];
    double d0 = (double)xb[(size_t)j*3]   - xi0;
    double d1 = (double)xb[(size_t)j*3+1] - xi1;
    double d2 = (double)xb[(size_t)j*3+2] - xi2;
    rotd[tid][0] = R1v[0]*d0 + R1v[1]*d1 + R1v[2]*d2;
    rotd[tid][1] = R1v[3]*d0 + R1v[4]*d1 + R1v[5]*d2;
    rotd[tid][2] = R1v[6]*d0 + R1v[7]*d1 + R1v[8]*d2;
  }
  __syncthreads();
  double mx = 0.0, my = 0.0;
  #pragma unroll
  for (int k = 0; k < K; ++k) { mx += rotd[k][0]; my += rotd[k][1]; }
  mx /= 20.0; my /= 20.0;
  double r = sqrt(mx*mx + my*my);
  double ct = 1.0, st = 0.0;
  if (r > 0.0) { ct = mx / r; st = my / r; }   // cos/sin of atan2(my,mx)
  if (tid < K) {
    double r0 = rotd[tid][0], r1 = rotd[tid][1], r2 = rotd[tid][2];
    double a0 = ct*r0 + st*r1;
    double a1 = ct*r1 - st*r0;
    fld[tid][0] = a0;  fld[tid][1] = a1;   fld[tid][2] = r2;
    fld[tid][3] = a0;  fld[tid][4] = -a1;  fld[tid][5] = r2;   // xz-mirror
    fld[tid][6] = xi0; fld[tid][7] = xi1;  fld[tid][8] = xi2;  // x_rep
  }
  if (PASS == 0 && tid == 0) {
    float* o1 = outR1 + (size_t)p * 9;
    #pragma unroll
    for (int i = 0; i < 9; ++i) o1[i] = (float)R1v[i];
    float* o2 = outR2 + (size_t)p * 9;
    o2[0] = (float)ct;  o2[1] = (float)st; o2[2] = 0.f;
    o2[3] = (float)-st; o2[4] = (float)ct; o2[5] = 0.f;
    o2[6] = 0.f;        o2[7] = 0.f;       o2[8] = 1.f;
  }
  __syncthreads();
  int o = tid;
  if (PASS == 0) {
    double sum = 0., sq = 0.;
    #pragma unroll
    for (int k = 0; k < K; ++k) {
      double h = 0.;
      #pragma unroll
      for (int c = 0; c < 9; ++c) h = fma((double)wl[o*9 + c], fld[k][c], h);
      sum += h; sq += h*h;
    }
    int slice = p & (NSLICE - 1);
    atomicAdd(&sS[slice*C3 + o], sum);
    atomicAdd(&sQ[slice*C3 + o], sq);
  } else {
    double m = mid[o], is = mid[C3 + o];
    double g = g1[o], bb = b1[o];
    double mxv = -INFINITY;
    #pragma unroll
    for (int k = 0; k < K; ++k) {
      double h = 0.;
      #pragma unroll
      for (int c = 0; c < 9; ++c) h = fma((double)wl[o*9 + c], fld[k][c], h);
      double y = ((h - m) * is) * g + bb;
      y = y > 0.0 ? y : 0.2 * y;
      mxv = fmax(mxv, y);
    }
    x1d[(size_t)p*C1 + o] = mxv;
    out448[(size_t)p*448 + o] = (float)mxv;
  }
}

// ---- conv2 (two-pass, f64): LDS-staged gather, BIT-EXACT op sequence:
// per acc[k]: phase1 c=0..63 fma(w[c], xj[c]-xi[c]); phase2 c=0..63 fma(w[64+c], xi[c]).
// The sub is precomputed once per block in LDS (identical f64 rounding). ----
template<int PASS>
__global__ __launch_bounds__(128) void conv2_kernel(
    const double* __restrict__ x1d, const int* __restrict__ idx,
    const float* __restrict__ w,
    double* __restrict__ sS, double* __restrict__ sQ,
    const double* __restrict__ mid, const float* __restrict__ gam, const float* __restrict__ bet,
    double* __restrict__ x2d, float* __restrict__ out448) {
  int p = blockIdx.x;
  int tid = threadIdx.x;
  int b = p >> 11;
  __shared__ double difL[K][C1];
  __shared__ double xiL[C1];
  __shared__ int jidx[K];
  if (tid < K) jidx[tid] = idx[(size_t)p*K + tid];
  if (tid < C1) xiL[tid] = x1d[(size_t)p*C1 + tid];
  __syncthreads();
  #pragma unroll
  for (int i = tid; i < K*C1; i += 128) {
    int k = i >> 6, c = i & 63;
    difL[k][c] = x1d[((size_t)b*N + jidx[k])*C1 + c] - xiL[c];
  }
  __syncthreads();
  const float* wr = w + (size_t)tid * (2*C1);
  double acc[K];
  #pragma unroll
  for (int k = 0; k < K; ++k) acc[k] = 0.0;
  // phase 1: diff operand, c ascending
  #pragma unroll
  for (int c0 = 0; c0 < C1; c0 += 16) {
    double wd[16];
    #pragma unroll
    for (int i = 0; i < 16; ++i) wd[i] = (double)wr[c0+i];
    #pragma unroll
    for (int k = 0; k < K; ++k) {
      #pragma unroll
      for (int i = 0; i < 16; ++i) acc[k] = fma(wd[i], difL[k][c0+i], acc[k]);
    }
  }
  // phase 2: x_rep operand, c ascending
  #pragma unroll
  for (int c0 = 0; c0 < C1; c0 += 16) {
    double wd[16], xiv[16];
    #pragma unroll
    for (int i = 0; i < 16; ++i) { wd[i] = (double)wr[C1+c0+i]; xiv[i] = xiL[c0+i]; }
    #pragma unroll
    for (int k = 0; k < K; ++k) {
      #pragma unroll
      for (int i = 0; i < 16; ++i) acc[k] = fma(wd[i], xiv[i], acc[k]);
    }
  }
  if (PASS == 0) {
    double sum = 0., sq = 0.;
    #pragma unroll
    for (int k = 0; k < K; ++k) { sum += acc[k]; sq += acc[k]*acc[k]; }
    int slice = p & (NSLICE - 1);
    atomicAdd(&sS[slice*C3 + tid], sum);
    atomicAdd(&sQ[slice*C3 + tid], sq);
  } else {
    double m = mid[tid], is = mid[C3 + tid];
    double g = gam[tid], bb = bet[tid];
    double mxv = -INFINITY;
    #pragma unroll
    for (int k = 0; k < K; ++k) {
      double y = ((acc[k] - m) * is) * g + bb;
      y = y > 0.0 ? y : 0.2 * y;
      mxv = fmax(mxv, y);
    }
    x2d[(size_t)p*C2 + tid] = mxv;
    out448[(size_t)p*448 + C1 + tid] = (float)mxv;
  }
}

// ---- conv3 (two-pass, f32, value path): folded algebra + LDS-staged gather ----
template<int PASS>
__global__ __launch_bounds__(256) void conv3_kernel(
    const float* __restrict__ x2f, const int* __restrict__ idx,
    const float* __restrict__ w,
    double* __restrict__ sS, double* __restrict__ sQ,
    const double* __restrict__ mid, const float* __restrict__ gam, const float* __restrict__ bet,
    float* __restrict__ out448) {
  int p = blockIdx.x;
  int tid = threadIdx.x;
  int b = p >> 11;
  __shared__ float xjL[K][C2];
  __shared__ float xiL[C2];
  __shared__ int jidx[K];
  if (tid < K) jidx[tid] = idx[(size_t)p*K + tid];
  if (tid < C2) xiL[tid] = x2f[(size_t)p*C2 + tid];
  __syncthreads();
  #pragma unroll
  for (int i = tid; i < K*C2; i += 256) {
    int k = i >> 7, c = i & 127;
    xjL[k][c] = x2f[((size_t)b*N + jidx[k])*C2 + c];
  }
  __syncthreads();
  const float* wr = w + (size_t)tid * (2*C2);
  float base = 0.f;
  #pragma unroll
  for (int c0 = 0; c0 < C2; c0 += 32) {
    #pragma unroll
    for (int i = 0; i < 32; ++i)
      base = fmaf(wr[C2+c0+i] - wr[c0+i], xiL[c0+i], base);
  }
  float acc[K];
  #pragma unroll
  for (int k = 0; k < K; ++k) acc[k] = base;
  #pragma unroll
  for (int c0 = 0; c0 < C2; c0 += 32) {
    float wd[32];
    #pragma unroll
    for (int i = 0; i < 32; ++i) wd[i] = wr[c0+i];
    #pragma unroll
    for (int k = 0; k < K; ++k) {
      #pragma unroll
      for (int i = 0; i < 32; ++i) acc[k] = fmaf(wd[i], xjL[k][c0+i], acc[k]);
    }
  }
  if (PASS == 0) {
    double sum = 0., sq = 0.;
    #pragma unroll
    for (int k = 0; k < K; ++k) {
      double h = (double)acc[k];
      sum += h; sq += h*h;
    }
    int slice = p & (NSLICE - 1);
    atomicAdd(&sS[slice*C3 + tid], sum);
    atomicAdd(&sQ[slice*C3 + tid], sq);
  } else {
    float m = (float)mid[tid], is = (float)mid[C3 + tid];
    float g = gam[tid], bb = bet[tid];
    float mxv = -INFINITY;
    #pragma unroll
    for (int k = 0; k < K; ++k) {
      float y = (acc[k] - m) * is * g + bb;
      y = y > 0.f ? y : 0.2f * y;
      mxv = fmaxf(mxv, y);
    }
    out448[(size_t)p*448 + C1 + C2 + tid] = mxv;
  }
}

// ---- finalize BN stats (f64) ----
__global__ void finalize_stats(const double* __restrict__ sS, const double* __restrict__ sQ,
                               double* __restrict__ mid, int C) {
  int o = threadIdx.x;
  if (o >= C) return;
  double s = 0., q = 0.;
  for (int i = 0; i < NSLICE; ++i) { s += sS[i*C3 + o]; q += sQ[i*C3 + o]; }
  double m = s / COUNT;
  double v = q / COUNT - m*m;
  mid[o] = m;
  mid[C3 + o] = 1.0 / sqrt(v + BNEPS);
}

} // namespace

extern "C" void kernel_launch(void* const* d_in, const int* in_sizes, int n_in,
                              void* d_out, int out_size, void* d_ws, size_t ws_size,
                              hipStream_t stream) {
  (void)in_sizes; (void)n_in; (void)out_size; (void)ws_size;
  const float* x   = (const float*)d_in[0];
  const float* nrm = (const float*)d_in[1];
  const float* w1  = (const float*)d_in[2];
  const float* g1  = (const float*)d_in[3];
  const float* b1  = (const float*)d_in[4];
  const float* w2  = (const float*)d_in[5];
  const float* g2  = (const float*)d_in[6];
  const float* b2  = (const float*)d_in[7];
  const float* w3  = (const float*)d_in[8];
  const float* g3  = (const float*)d_in[9];
  const float* b3  = (const float*)d_in[10];
  float* out = (float*)d_out;
  char*  ws  = (char*)d_ws;

  int*    idx1 = (int*)(ws + OFF_IDX1);
  int*    idx2 = (int*)(ws + OFF_IDX2);
  double* x1d  = (double*)(ws + OFF_X1D);
  double* x2d  = (double*)(ws + OFF_X2D);
  double* sS   = (double*)(ws + OFF_STATS);
  double* sQ   = sS + (size_t)NSLICE * C3;
  double* mid  = (double*)(ws + OFF_MI);
  float*  x2f  = (float*)(ws + OFF_X2F);
  float*  xx2f = (float*)(ws + OFF_XX2F);
  float*  dist = (float*)(ws + OFF_DIST);   // all batches

  float* outR1 = out + (size_t)B * N * 448;
  float* outR2 = outR1 + (size_t)B * N * 9;

  // kNN1 — numpy-f32-faithful formula
  knn_xyz_f32<<<B*N/64, 64, 0, stream>>>(x, idx1);

  // layer 1 (f64 two-pass)
  hipMemsetAsync(sS, 0, (size_t)2*NSLICE*C3*sizeof(double), stream);
  l1_kernel<0><<<B*N, 64, 0, stream>>>(x, nrm, w1, idx1, sS, sQ, nullptr, nullptr, nullptr,
                                       nullptr, nullptr, outR1, outR2);
  finalize_stats<<<1, C3, 0, stream>>>(sS, sQ, mid, C1);
  l1_kernel<1><<<B*N, 64, 0, stream>>>(x, nrm, w1, idx1, nullptr, nullptr, mid, g1, b1,
                                       x1d, out, outR1, outR2);

  // layer 2 (f64 two-pass, LDS-staged, bit-exact op order)
  hipMemsetAsync(sS, 0, (size_t)2*NSLICE*C3*sizeof(double), stream);
  conv2_kernel<0><<<B*N, 128, 0, stream>>>(x1d, idx1, w2, sS, sQ, nullptr, nullptr, nullptr,
                                           nullptr, nullptr);
  finalize_stats<<<1, C3, 0, stream>>>(sS, sQ, mid, C2);
  conv2_kernel<1><<<B*N, 128, 0, stream>>>(x1d, idx1, w2, nullptr, nullptr, mid, g2, b2,
                                           x2d, out);

  // kNN2 — numpy-f32-faithful, all batches fused
  xx2f_kernel<<<B*N/64, 64, 0, stream>>>(x2d, x2f, xx2f);
  dist_f32_kernel<<<dim3(N/64, N/64, B), 256, 0, stream>>>(x2f, xx2f, dist);
  knn_feat_f32<<<B*N/64, 64, 0, stream>>>(dist, idx2);

  // layer 3 (f32 two-pass, folded, LDS-staged, value path)
  hipMemsetAsync(sS, 0, (size_t)2*NSLICE*C3*sizeof(double), stream);
  conv3_kernel<0><<<B*N, 256, 0, stream>>>(x2f, idx2, w3, sS, sQ, nullptr, nullptr, nullptr,
                                           nullptr);
  finalize_stats<<<1, C3, 0, stream>>>(sS, sQ, mid, C3);
  conv3_kernel<1><<<B*N, 256, 0, stream>>>(x2f, idx2, w3, nullptr, nullptr, mid, g3, b3,
                                           out);
}